// Round 9
// baseline (102.338 us; speedup 1.0000x reference)
//
#include <hip/hip_runtime.h>
#include <math.h>

typedef __bf16 bf16x8 __attribute__((ext_vector_type(8)));
typedef float  f32x4  __attribute__((ext_vector_type(4)));
typedef float  vf4    __attribute__((ext_vector_type(4)));

__device__ __forceinline__ float wave_sum(float v) {
#pragma unroll
    for (int m = 1; m < 64; m <<= 1) v += __shfl_xor(v, m, 64);
    return v;
}

__device__ __forceinline__ unsigned short f2bf(float f) {
    union { float f; unsigned int u; } x; x.f = f;
    unsigned int u = x.u;
    u += 0x7fffu + ((u >> 16) & 1u);   // round-to-nearest-even
    return (unsigned short)(u >> 16);
}
__device__ __forceinline__ float bf2f(unsigned short h) {
    union { unsigned int u; float f; } x; x.u = ((unsigned int)h) << 16;
    return x.f;
}
// pack value+residual as u32 (hi|lo<<16)
__device__ __forceinline__ unsigned packsplit(float v) {
    const unsigned short h = f2bf(v);
    const unsigned short l = f2bf(v - bf2f(h));
    return (unsigned)h | ((unsigned)l << 16);
}

__device__ __forceinline__ float4 ntload4(const float* p) {
    const vf4 v = __builtin_nontemporal_load((const vf4*)p);
    return make_float4(v.x, v.y, v.z, v.w);
}

// ------- weight convert to MFMA fragment-linear layout (unchanged) ---------
__global__ __launch_bounds__(256) void k_wconv(
    const float* __restrict__ w_qc, const float* __restrict__ w_k,
    const float* __restrict__ w_v, const float* __restrict__ w_qf,
    unsigned short* __restrict__ WfragC_hi, unsigned short* __restrict__ WfragC_lo,
    unsigned short* __restrict__ WfragQ_hi, unsigned short* __restrict__ WfragQ_lo)
{
    const int t = blockIdx.x * 256 + threadIdx.x;
    if (t < 24576) {
        const int lane = t & 63, kk = (t >> 6) & 15, nf = t >> 10;
        const int n  = nf * 16 + (lane & 15);
        const int k0 = kk * 32 + (lane >> 4) * 8;
        const float* src; int col, w;
        if (n < 64)       { src = w_qc; col = n;       w = 64;  }
        else if (n < 128) { src = w_k;  col = n - 64;  w = 64;  }
        else              { src = w_v;  col = n - 128; w = 256; }
        unsigned hi[4], lo[4];
#pragma unroll
        for (int i = 0; i < 4; ++i) {
            const float v0 = src[(size_t)(k0 + 2*i)     * w + col];
            const float v1 = src[(size_t)(k0 + 2*i + 1) * w + col];
            const unsigned short h0 = f2bf(v0), h1 = f2bf(v1);
            hi[i] = (unsigned)h0 | ((unsigned)h1 << 16);
            lo[i] = (unsigned)f2bf(v0 - bf2f(h0)) | ((unsigned)f2bf(v1 - bf2f(h1)) << 16);
        }
        *(uint4*)&WfragC_hi[(size_t)t * 8] = *(const uint4*)hi;
        if (nf < 8) *(uint4*)&WfragC_lo[(size_t)t * 8] = *(const uint4*)lo;
    } else if (t < 24576 + 2048) {
        const int t2 = t - 24576;
        const int lane = t2 & 63, kk = (t2 >> 6) & 7, nf = t2 >> 9;
        const int n  = nf * 16 + (lane & 15);
        const int k0 = kk * 32 + (lane >> 4) * 8;
        unsigned hi[4], lo[4];
#pragma unroll
        for (int i = 0; i < 4; ++i) {
            const float v0 = w_qf[(size_t)(k0 + 2*i)     * 64 + n];
            const float v1 = w_qf[(size_t)(k0 + 2*i + 1) * 64 + n];
            const unsigned short h0 = f2bf(v0), h1 = f2bf(v1);
            hi[i] = (unsigned)h0 | ((unsigned)h1 << 16);
            lo[i] = (unsigned)f2bf(v0 - bf2f(h0)) | ((unsigned)f2bf(v1 - bf2f(h1)) << 16);
        }
        *(uint4*)&WfragQ_hi[(size_t)t2 * 8] = *(const uint4*)hi;
        *(uint4*)&WfragQ_lo[(size_t)t2 * 8] = *(const uint4*)lo;
    }
}

// ---------------- Kernel 1: coarse LN + gate + MFMA GEMM -------------------
// outputs: qc f32, key packed-split u32, value bf16
#define AP 520
__global__ __launch_bounds__(512) void k_coarse_fused(
    const float* __restrict__ coarse,
    const float* __restrict__ ln_g, const float* __restrict__ ln_b,
    const float* __restrict__ w_gate, const float* __restrict__ b_gate,
    const unsigned short* __restrict__ WfragC_hi,
    const unsigned short* __restrict__ WfragC_lo,
    const float* __restrict__ b_qc, const float* __restrict__ b_k,
    const float* __restrict__ b_v,
    float* __restrict__ gate_o, float* __restrict__ qc_o,
    unsigned* __restrict__ key_pk, unsigned short* __restrict__ val_b)
{
    __shared__ unsigned short Ah[32 * AP];
    __shared__ unsigned short Al[32 * AP];
    const int tid = threadIdx.x;
    const int lane = tid & 63, wave = tid >> 6;
    const int ci0 = blockIdx.x << 5;

    for (int pp = 0; pp < 4; ++pp) {
        const int p = (wave << 2) + pp;
        const float* src = coarse + (size_t)(ci0 + p) * 512;
        const int c0 = lane * 4, c1 = 256 + lane * 4;
        const float4 x0 = ntload4(src + c0);
        const float4 x1 = ntload4(src + c1);
        float s = (x0.x + x0.y) + (x0.z + x0.w) + (x1.x + x1.y) + (x1.z + x1.w);
        float sq = x0.x*x0.x + x0.y*x0.y + x0.z*x0.z + x0.w*x0.w
                 + x1.x*x1.x + x1.y*x1.y + x1.z*x1.z + x1.w*x1.w;
        s = wave_sum(s); sq = wave_sum(sq);
        const float mean = s * (1.0f / 512.0f);
        const float var  = sq * (1.0f / 512.0f) - mean * mean;
        const float inv  = rsqrtf(var + 1e-3f);
        const float4 g0 = *(const float4*)(ln_g + c0), g1 = *(const float4*)(ln_g + c1);
        const float4 h0 = *(const float4*)(ln_b + c0), h1 = *(const float4*)(ln_b + c1);
        float y[8];
        y[0] = (x0.x - mean) * inv * g0.x + h0.x;
        y[1] = (x0.y - mean) * inv * g0.y + h0.y;
        y[2] = (x0.z - mean) * inv * g0.z + h0.z;
        y[3] = (x0.w - mean) * inv * g0.w + h0.w;
        y[4] = (x1.x - mean) * inv * g1.x + h1.x;
        y[5] = (x1.y - mean) * inv * g1.y + h1.y;
        y[6] = (x1.z - mean) * inv * g1.z + h1.z;
        y[7] = (x1.w - mean) * inv * g1.w + h1.w;
        unsigned short* ah = Ah + p * AP;
        unsigned short* al = Al + p * AP;
#pragma unroll
        for (int j = 0; j < 8; ++j) {
            const int c = (j < 4) ? (c0 + j) : (c1 + j - 4);
            const unsigned short h = f2bf(y[j]);
            ah[c] = h;
            al[c] = f2bf(y[j] - bf2f(h));
        }
        const float4 wg0 = *(const float4*)(w_gate + c0), wg1 = *(const float4*)(w_gate + c1);
        float gd = y[0]*wg0.x + y[1]*wg0.y + y[2]*wg0.z + y[3]*wg0.w
                 + y[4]*wg1.x + y[5]*wg1.y + y[6]*wg1.z + y[7]*wg1.w;
        gd = wave_sum(gd);
        if (lane == 0) gate_o[ci0 + p] = 1.0f / (1.0f + __expf(-(gd + b_gate[0])));
    }
    __syncthreads();

    const int lrow = lane & 15, m16 = lane & 15, lk = (lane >> 4) * 8;
    f32x4 acc_s[2], acc_v[2][2];
#pragma unroll
    for (int i = 0; i < 2; ++i) {
        acc_s[i] = (f32x4){0.f, 0.f, 0.f, 0.f};
        acc_v[i][0] = (f32x4){0.f, 0.f, 0.f, 0.f};
        acc_v[i][1] = (f32x4){0.f, 0.f, 0.f, 0.f};
    }

    const unsigned short* Fs_h = WfragC_hi + ((size_t)(wave * 16) * 64 + lane) * 8;
    const unsigned short* Fs_l = WfragC_lo + ((size_t)(wave * 16) * 64 + lane) * 8;
    const unsigned short* Fv0  = WfragC_hi + ((size_t)((8 + 2*wave) * 16) * 64 + lane) * 8;
    const unsigned short* Fv1  = WfragC_hi + ((size_t)((9 + 2*wave) * 16) * 64 + lane) * 8;
    const int KSTEP = 64 * 8;

    bf16x8 pbh[4], pbl[4], pv0[4], pv1[4];
#pragma unroll
    for (int i = 0; i < 4; ++i) {
        pbh[i] = *(const bf16x8*)(Fs_h + i * KSTEP);
        pbl[i] = *(const bf16x8*)(Fs_l + i * KSTEP);
        pv0[i] = *(const bf16x8*)(Fv0 + i * KSTEP);
        pv1[i] = *(const bf16x8*)(Fv1 + i * KSTEP);
    }

#pragma unroll
    for (int kk = 0; kk < 16; ++kk) {
        const int cur = kk & 3;
        const bf16x8 bh = pbh[cur], bl = pbl[cur], v0 = pv0[cur], v1 = pv1[cur];
        if (kk < 12) {
            pbh[cur] = *(const bf16x8*)(Fs_h + (kk + 4) * KSTEP);
            pbl[cur] = *(const bf16x8*)(Fs_l + (kk + 4) * KSTEP);
            pv0[cur] = *(const bf16x8*)(Fv0 + (kk + 4) * KSTEP);
            pv1[cur] = *(const bf16x8*)(Fv1 + (kk + 4) * KSTEP);
        }
        bf16x8 ah[2], alo[2];
#pragma unroll
        for (int mf = 0; mf < 2; ++mf) {
            ah[mf]  = *(const bf16x8*)&Ah[(mf * 16 + lrow) * AP + kk * 32 + lk];
            alo[mf] = *(const bf16x8*)&Al[(mf * 16 + lrow) * AP + kk * 32 + lk];
        }
#pragma unroll
        for (int mf = 0; mf < 2; ++mf) {
            acc_s[mf] = __builtin_amdgcn_mfma_f32_16x16x32_bf16(ah[mf],  bh, acc_s[mf], 0, 0, 0);
            acc_s[mf] = __builtin_amdgcn_mfma_f32_16x16x32_bf16(alo[mf], bh, acc_s[mf], 0, 0, 0);
            acc_s[mf] = __builtin_amdgcn_mfma_f32_16x16x32_bf16(ah[mf],  bl, acc_s[mf], 0, 0, 0);
            acc_v[mf][0] = __builtin_amdgcn_mfma_f32_16x16x32_bf16(ah[mf], v0, acc_v[mf][0], 0, 0, 0);
            acc_v[mf][1] = __builtin_amdgcn_mfma_f32_16x16x32_bf16(ah[mf], v1, acc_v[mf][1], 0, 0, 0);
        }
    }

    // --- epilogue: qc f32, key packed-split, value bf16 ---
    const int rbase = (lane >> 4) * 4;
    const int ns = wave * 16 + m16;
#pragma unroll
    for (int mf = 0; mf < 2; ++mf) {
#pragma unroll
        for (int r = 0; r < 4; ++r) {
            const int m = mf * 16 + rbase + r;
            const int ci = ci0 + m;
            const float vs = acc_s[mf][r];
            if (ns < 64) qc_o[(size_t)ci * 64 + ns] = vs + b_qc[ns];
            else         key_pk[(size_t)ci * 64 + ns - 64] = packsplit(vs + b_k[ns - 64]);
#pragma unroll
            for (int vv = 0; vv < 2; ++vv) {
                const int ch = wave * 32 + vv * 16 + m16;
                val_b[(size_t)ci * 256 + ch] = f2bf(acc_v[mf][vv][r] + b_v[ch]);
            }
        }
    }
}

// ---------------- Kernel 2: fine LN + qf + gating -> query packed-split ----
#define QP 264
__global__ __launch_bounds__(256) void k_query_fused(
    const float* __restrict__ fine,
    const float* __restrict__ ln_g, const float* __restrict__ ln_b,
    const unsigned short* __restrict__ WfragQ_hi,
    const unsigned short* __restrict__ WfragQ_lo,
    const float* __restrict__ b_qf,
    const float* __restrict__ gate_i, const float* __restrict__ qc_i,
    unsigned* __restrict__ qry_pk)
{
    __shared__ unsigned short Ah[32 * QP];
    __shared__ unsigned short Al[32 * QP];
    const int tid = threadIdx.x;
    const int lane = tid & 63, wave = tid >> 6;
    const int fp0 = blockIdx.x << 5;

    for (int pp = 0; pp < 8; ++pp) {
        const int p = (wave << 3) + pp;
        const float* src = fine + (size_t)(fp0 + p) * 256;
        const int c0 = lane * 4;
        const float4 x = ntload4(src + c0);
        float s = (x.x + x.y) + (x.z + x.w);
        float sq = x.x*x.x + x.y*x.y + x.z*x.z + x.w*x.w;
        s = wave_sum(s); sq = wave_sum(sq);
        const float mean = s * (1.0f / 256.0f);
        const float var  = sq * (1.0f / 256.0f) - mean * mean;
        const float inv  = rsqrtf(var + 1e-3f);
        const float4 g = *(const float4*)(ln_g + c0);
        const float4 h = *(const float4*)(ln_b + c0);
        float y[4];
        y[0] = (x.x - mean) * inv * g.x + h.x;
        y[1] = (x.y - mean) * inv * g.y + h.y;
        y[2] = (x.z - mean) * inv * g.z + h.z;
        y[3] = (x.w - mean) * inv * g.w + h.w;
        unsigned short* ah = Ah + p * QP;
        unsigned short* al = Al + p * QP;
#pragma unroll
        for (int j = 0; j < 4; ++j) {
            const unsigned short hh = f2bf(y[j]);
            ah[c0 + j] = hh;
            al[c0 + j] = f2bf(y[j] - bf2f(hh));
        }
    }
    __syncthreads();

    const int lrow = lane & 15, lk = (lane >> 4) * 8;
    f32x4 acc[2];
    acc[0] = (f32x4){0.f, 0.f, 0.f, 0.f};
    acc[1] = (f32x4){0.f, 0.f, 0.f, 0.f};

    const unsigned short* Fh = WfragQ_hi + ((size_t)(wave * 8) * 64 + lane) * 8;
    const unsigned short* Fl = WfragQ_lo + ((size_t)(wave * 8) * 64 + lane) * 8;
    const int KSTEP = 64 * 8;
    bf16x8 pbh[4], pbl[4];
#pragma unroll
    for (int i = 0; i < 4; ++i) {
        pbh[i] = *(const bf16x8*)(Fh + i * KSTEP);
        pbl[i] = *(const bf16x8*)(Fl + i * KSTEP);
    }

#pragma unroll
    for (int kk = 0; kk < 8; ++kk) {
        const int cur = kk & 3;
        const bf16x8 bh = pbh[cur], bl = pbl[cur];
        if (kk < 4) {
            pbh[cur] = *(const bf16x8*)(Fh + (kk + 4) * KSTEP);
            pbl[cur] = *(const bf16x8*)(Fl + (kk + 4) * KSTEP);
        }
#pragma unroll
        for (int mf = 0; mf < 2; ++mf) {
            const bf16x8 ah = *(const bf16x8*)&Ah[(mf * 16 + lrow) * QP + kk * 32 + lk];
            const bf16x8 al = *(const bf16x8*)&Al[(mf * 16 + lrow) * QP + kk * 32 + lk];
            acc[mf] = __builtin_amdgcn_mfma_f32_16x16x32_bf16(ah, bh, acc[mf], 0, 0, 0);
            acc[mf] = __builtin_amdgcn_mfma_f32_16x16x32_bf16(al, bh, acc[mf], 0, 0, 0);
            acc[mf] = __builtin_amdgcn_mfma_f32_16x16x32_bf16(ah, bl, acc[mf], 0, 0, 0);
        }
    }

    const int n = wave * 16 + (lane & 15);
    const float bias = b_qf[n];
    const int rbase = (lane >> 4) * 4;
#pragma unroll
    for (int mf = 0; mf < 2; ++mf) {
#pragma unroll
        for (int r = 0; r < 4; ++r) {
            const int m = mf * 16 + rbase + r;
            const int fp = fp0 + m;
            const int wx = fp & 127, h = (fp >> 7) & 127, b2 = fp >> 14;
            const int ci = ((b2 << 6) + (h >> 1)) * 64 + (wx >> 1);
            const float gt = gate_i[ci];
            const float qcv = qc_i[(size_t)ci * 64 + n];
            qry_pk[(size_t)fp * 64 + n] = packsplit((acc[mf][r] + bias) * gt + qcv * (1.0f - gt));
        }
    }
}

// ---------------- Kernel 3: MFMA 5x5 local attention -----------------------
#define LDS_K_HI 0
#define LDS_K_LO 4096
#define LDS_VT   8192
#define LDS_ATT  26624
__global__ __launch_bounds__(256) void k_attn_mfma(
    const unsigned* __restrict__ qry_pk, const unsigned* __restrict__ key_pk,
    const unsigned short* __restrict__ val_b, float* __restrict__ out)
{
    __shared__ unsigned short LDS[30720];
    const int tid = threadIdx.x;
    const int lane = tid & 63, wave = tid >> 6;
    const int m16 = lane & 15, g4 = lane >> 4;
    // XCD-chunked swizzle: grid 1024 = 8 XCDs x 128 contiguous blocks
    const int blk0 = blockIdx.x;
    const int blk = (blk0 & 7) * 128 + (blk0 >> 3);
    const int bx = blk & 15, by = (blk >> 4) & 15, bb = blk >> 8;
    const int cy0 = by << 2, cx0 = bx << 2;

    // ---- stage K (packed split u32 -> hi/lo granule planes) ----
    {
        const int tau = lane, chunk = wave;
        const int cy = cy0 - 2 + (tau >> 3), cx = cx0 - 2 + (tau & 7);
        unsigned w[16];
        if ((unsigned)cy < 64u && (unsigned)cx < 64u) {
            const unsigned* src = key_pk + ((size_t)(((bb << 6) + cy) << 6) + cx) * 64 + chunk * 16;
#pragma unroll
            for (int i = 0; i < 4; ++i)
                *(uint4*)&w[i * 4] = *(const uint4*)(src + i * 4);
        } else {
#pragma unroll
            for (int i = 0; i < 16; ++i) w[i] = 0u;
        }
#pragma unroll
        for (int g = 0; g < 2; ++g) {
            unsigned hi[4], lo[4];
#pragma unroll
            for (int i = 0; i < 4; ++i) {
                const unsigned w0 = w[g * 8 + 2 * i], w1 = w[g * 8 + 2 * i + 1];
                hi[i] = (w0 & 0xffffu) | ((w1 & 0xffffu) << 16);
                lo[i] = (w0 >> 16) | (w1 & 0xffff0000u);
            }
            const int G = chunk * 2 + g;
            const int a = tau * 64 + ((G ^ (tau & 7)) * 8);
            *(uint4*)&LDS[LDS_K_HI + a] = *(const uint4*)hi;
            *(uint4*)&LDS[LDS_K_LO + a] = *(const uint4*)lo;
        }
    }

    // ---- stage V^T [ch][pos] bf16 pitch 72 (bf16 source: half traffic) ----
    {
        const int p2 = lane & 31;
        const int pos0 = p2 * 2;
        const int cy = cy0 - 2 + (pos0 >> 3);
        const int cx = cx0 - 2 + (pos0 & 7);
        const bool ok0 = ((unsigned)cy < 64u) && ((unsigned)cx < 64u);
        const bool ok1 = ((unsigned)cy < 64u) && ((unsigned)(cx + 1) < 64u);
        const size_t base0 = ((size_t)(((bb << 6) + cy) << 6) + cx) * 256;
        const int chbase = wave * 64 + (lane >> 5) * 8;
        const uint4 z = {0u, 0u, 0u, 0u};
#pragma unroll
        for (int it = 0; it < 4; ++it) {
            const int ch = chbase + it * 16;
            const uint4 a = ok0 ? *(const uint4*)(val_b + base0 + ch) : z;
            const uint4 b = ok1 ? *(const uint4*)(val_b + base0 + 256 + ch) : z;
            const unsigned short* au = (const unsigned short*)&a;
            const unsigned short* bu = (const unsigned short*)&b;
#pragma unroll
            for (int j = 0; j < 8; ++j) {
                const unsigned w = (unsigned)au[j] | ((unsigned)bu[j] << 16);
                *(unsigned*)&LDS[LDS_VT + (ch + j) * 72 + pos0] = w;
            }
        }
    }

    // ---- zero att ----
    {
        const uint4 z = {0u, 0u, 0u, 0u};
        *(uint4*)&LDS[LDS_ATT + tid * 8] = z;
        *(uint4*)&LDS[LDS_ATT + 2048 + tid * 8] = z;
    }

    // ---- load q frags (packed split u32 -> qh/ql) ----
    const int fybase = (by << 3) + (wave << 1);
    bf16x8 qh[2], ql[2];
    {
        const int fy = fybase + (m16 >> 3);
        const int fx = (bx << 3) + (m16 & 7);
        const unsigned* qsrc = qry_pk + ((size_t)(((bb << 7) + fy) << 7) + fx) * 64;
#pragma unroll
        for (int kf = 0; kf < 2; ++kf) {
            unsigned w[8];
            *(uint4*)&w[0] = *(const uint4*)(qsrc + kf * 32 + g4 * 8);
            *(uint4*)&w[4] = *(const uint4*)(qsrc + kf * 32 + g4 * 8 + 4);
            union { unsigned u[4]; bf16x8 b; } uh, ul;
#pragma unroll
            for (int i = 0; i < 4; ++i) {
                const unsigned w0 = w[2 * i], w1 = w[2 * i + 1];
                uh.u[i] = (w0 & 0xffffu) | ((w1 & 0xffffu) << 16);
                ul.u[i] = (w0 >> 16) | (w1 & 0xffff0000u);
            }
            qh[kf] = uh.b; ql[kf] = ul.b;
        }
    }

    __syncthreads();

    // ---- scores ----
    f32x4 sc[3];
#pragma unroll
    for (int nf = 0; nf < 3; ++nf) sc[nf] = (f32x4){0.f, 0.f, 0.f, 0.f};
#pragma unroll
    for (int nf = 0; nf < 3; ++nf) {
        const int row = 8 * wave + nf * 16 + m16;
#pragma unroll
        for (int kf = 0; kf < 2; ++kf) {
            const int G = kf * 4 + g4;
            const int a = row * 64 + ((G ^ (m16 & 7)) * 8);
            const bf16x8 bh = *(const bf16x8*)&LDS[LDS_K_HI + a];
            const bf16x8 bl = *(const bf16x8*)&LDS[LDS_K_LO + a];
            sc[nf] = __builtin_amdgcn_mfma_f32_16x16x32_bf16(qh[kf], bh, sc[nf], 0, 0, 0);
            sc[nf] = __builtin_amdgcn_mfma_f32_16x16x32_bf16(ql[kf], bh, sc[nf], 0, 0, 0);
            sc[nf] = __builtin_amdgcn_mfma_f32_16x16x32_bf16(qh[kf], bl, sc[nf], 0, 0, 0);
        }
    }

    // ---- mask + softmax ----
    float e[3][4];
    float rinv[4];
#pragma unroll
    for (int r = 0; r < 4; ++r) {
        const int m = 4 * g4 + r;
        const int j = (m & 7) >> 1;
        float mr = -1e30f;
#pragma unroll
        for (int nf = 0; nf < 3; ++nf) {
            const int tf = nf * 16 + m16;
            const int tc = tf & 7;
            const bool c = (tf < 40) && (tc >= j) && (tc <= j + 4);
            e[nf][r] = c ? sc[nf][r] : -1e30f;
            mr = fmaxf(mr, e[nf][r]);
        }
#pragma unroll
        for (int msk = 1; msk < 16; msk <<= 1) mr = fmaxf(mr, __shfl_xor(mr, msk, 64));
        float s = 0.f;
#pragma unroll
        for (int nf = 0; nf < 3; ++nf) {
            const float ev = (e[nf][r] > -1e29f) ? __expf(e[nf][r] - mr) : 0.f;
            e[nf][r] = ev; s += ev;
        }
#pragma unroll
        for (int msk = 1; msk < 16; msk <<= 1) s += __shfl_xor(s, msk, 64);
        rinv[r] = 1.0f / s;
    }

    // ---- write att bf16, swizzled ----
#pragma unroll
    for (int nf = 0; nf < 3; ++nf) {
        const int t = 8 * wave + nf * 16 + m16;
        if (t < 64) {
#pragma unroll
            for (int r = 0; r < 4; ++r) {
                const int prow = wave * 16 + 4 * g4 + r;
                const int a = prow * 64 + (((t >> 3) ^ (prow & 7)) * 8) + (t & 7);
                LDS[LDS_ATT + a] = f2bf(e[nf][r] * rinv[r]);
            }
        }
    }

    // ---- PV ----
    bf16x8 af[2];
#pragma unroll
    for (int kf = 0; kf < 2; ++kf) {
        const int row = wave * 16 + m16;
        const int G = kf * 4 + g4;
        af[kf] = *(const bf16x8*)&LDS[LDS_ATT + row * 64 + ((G ^ (m16 & 7)) * 8)];
    }
    f32x4 ao[16];
#pragma unroll
    for (int nf = 0; nf < 16; ++nf) ao[nf] = (f32x4){0.f, 0.f, 0.f, 0.f};
#pragma unroll
    for (int nf = 0; nf < 16; ++nf) {
        const int ch = nf * 16 + m16;
#pragma unroll
        for (int kf = 0; kf < 2; ++kf) {
            const bf16x8 b = *(const bf16x8*)&LDS[LDS_VT + ch * 72 + kf * 32 + g4 * 8];
            ao[nf] = __builtin_amdgcn_mfma_f32_16x16x32_bf16(af[kf], b, ao[nf], 0, 0, 0);
        }
    }

    // ---- store ----
#pragma unroll
    for (int r = 0; r < 4; ++r) {
        const int m = 4 * g4 + r;
        const int fy = fybase + (m >> 3);
        const int fx = (bx << 3) + (m & 7);
        float* op = out + ((size_t)(((bb << 7) + fy) << 7) + fx) * 256 + m16;
#pragma unroll
        for (int nf = 0; nf < 16; ++nf)
            op[nf * 16] = ao[nf][r];
    }
}

// ---------------- launch ----------------
extern "C" void kernel_launch(void* const* d_in, const int* in_sizes, int n_in,
                              void* d_out, int out_size, void* d_ws, size_t ws_size,
                              hipStream_t stream)
{
    const float* fine   = (const float*)d_in[0];
    const float* coarse = (const float*)d_in[1];
    const float* ln_f_g = (const float*)d_in[2];
    const float* ln_f_b = (const float*)d_in[3];
    const float* ln_c_g = (const float*)d_in[4];
    const float* ln_c_b = (const float*)d_in[5];
    const float* w_gate = (const float*)d_in[6];
    const float* b_gate = (const float*)d_in[7];
    const float* w_qf   = (const float*)d_in[8];
    const float* b_qf   = (const float*)d_in[9];
    const float* w_qc   = (const float*)d_in[10];
    const float* b_qc   = (const float*)d_in[11];
    const float* w_k    = (const float*)d_in[12];
    const float* b_k    = (const float*)d_in[13];
    const float* w_v    = (const float*)d_in[14];
    const float* b_v    = (const float*)d_in[15];
    float* out = (float*)d_out;

    float* ws   = (float*)d_ws;
    float* gate = ws;                                           // 16384 f32
    float* qc   = gate + 16384;                                 // 16384*64 f32
    unsigned* key_pk = (unsigned*)(qc + (size_t)16384 * 64);    // 16384*64 u32
    unsigned short* val_b = (unsigned short*)(key_pk + (size_t)16384 * 64); // 16384*256 u16
    unsigned* qry_pk = (unsigned*)(val_b + (size_t)16384 * 256);            // 65536*64 u32
    unsigned short* WfragC_hi = (unsigned short*)(qry_pk + (size_t)65536 * 64);
    unsigned short* WfragC_lo = WfragC_hi + (size_t)24576 * 8;
    unsigned short* WfragQ_hi = WfragC_lo + (size_t)8192 * 8;
    unsigned short* WfragQ_lo = WfragQ_hi + (size_t)2048 * 8;

    k_wconv<<<104, 256, 0, stream>>>(w_qc, w_k, w_v, w_qf,
                                     WfragC_hi, WfragC_lo, WfragQ_hi, WfragQ_lo);
    k_coarse_fused<<<512, 512, 0, stream>>>(coarse, ln_c_g, ln_c_b, w_gate, b_gate,
                                            WfragC_hi, WfragC_lo, b_qc, b_k, b_v,
                                            gate, qc, key_pk, val_b);
    k_query_fused<<<2048, 256, 0, stream>>>(fine, ln_f_g, ln_f_b, WfragQ_hi, WfragQ_lo, b_qf,
                                            gate, qc, qry_pk);
    k_attn_mfma<<<1024, 256, 0, stream>>>(qry_pk, key_pk, val_b, out);
}

// Round 10
// 87.434 us; speedup vs baseline: 1.1705x; 1.1705x over previous
//
#include <hip/hip_runtime.h>
#include <math.h>

typedef __bf16 bf16x8 __attribute__((ext_vector_type(8)));
typedef float  f32x4  __attribute__((ext_vector_type(4)));
typedef float  vf4    __attribute__((ext_vector_type(4)));

__device__ __forceinline__ float wave_sum(float v) {
#pragma unroll
    for (int m = 1; m < 64; m <<= 1) v += __shfl_xor(v, m, 64);
    return v;
}

__device__ __forceinline__ unsigned short f2bf(float f) {
    union { float f; unsigned int u; } x; x.f = f;
    unsigned int u = x.u;
    u += 0x7fffu + ((u >> 16) & 1u);   // round-to-nearest-even
    return (unsigned short)(u >> 16);
}
__device__ __forceinline__ float bf2f(unsigned short h) {
    union { unsigned int u; float f; } x; x.u = ((unsigned int)h) << 16;
    return x.f;
}
__device__ __forceinline__ unsigned packsplit(float v) {
    const unsigned short h = f2bf(v);
    const unsigned short l = f2bf(v - bf2f(h));
    return (unsigned)h | ((unsigned)l << 16);
}
__device__ __forceinline__ float4 ntload4(const float* p) {
    const vf4 v = __builtin_nontemporal_load((const vf4*)p);
    return make_float4(v.x, v.y, v.z, v.w);
}

// ------- weight convert to MFMA fragment-linear layout (unchanged) ---------
__global__ __launch_bounds__(256) void k_wconv(
    const float* __restrict__ w_qc, const float* __restrict__ w_k,
    const float* __restrict__ w_v, const float* __restrict__ w_qf,
    unsigned short* __restrict__ WfragC_hi, unsigned short* __restrict__ WfragC_lo,
    unsigned short* __restrict__ WfragQ_hi, unsigned short* __restrict__ WfragQ_lo)
{
    const int t = blockIdx.x * 256 + threadIdx.x;
    if (t < 24576) {
        const int lane = t & 63, kk = (t >> 6) & 15, nf = t >> 10;
        const int n  = nf * 16 + (lane & 15);
        const int k0 = kk * 32 + (lane >> 4) * 8;
        const float* src; int col, w;
        if (n < 64)       { src = w_qc; col = n;       w = 64;  }
        else if (n < 128) { src = w_k;  col = n - 64;  w = 64;  }
        else              { src = w_v;  col = n - 128; w = 256; }
        unsigned hi[4], lo[4];
#pragma unroll
        for (int i = 0; i < 4; ++i) {
            const float v0 = src[(size_t)(k0 + 2*i)     * w + col];
            const float v1 = src[(size_t)(k0 + 2*i + 1) * w + col];
            const unsigned short h0 = f2bf(v0), h1 = f2bf(v1);
            hi[i] = (unsigned)h0 | ((unsigned)h1 << 16);
            lo[i] = (unsigned)f2bf(v0 - bf2f(h0)) | ((unsigned)f2bf(v1 - bf2f(h1)) << 16);
        }
        *(uint4*)&WfragC_hi[(size_t)t * 8] = *(const uint4*)hi;
        if (nf < 8) *(uint4*)&WfragC_lo[(size_t)t * 8] = *(const uint4*)lo;
    } else if (t < 24576 + 2048) {
        const int t2 = t - 24576;
        const int lane = t2 & 63, kk = (t2 >> 6) & 7, nf = t2 >> 9;
        const int n  = nf * 16 + (lane & 15);
        const int k0 = kk * 32 + (lane >> 4) * 8;
        unsigned hi[4], lo[4];
#pragma unroll
        for (int i = 0; i < 4; ++i) {
            const float v0 = w_qf[(size_t)(k0 + 2*i)     * 64 + n];
            const float v1 = w_qf[(size_t)(k0 + 2*i + 1) * 64 + n];
            const unsigned short h0 = f2bf(v0), h1 = f2bf(v1);
            hi[i] = (unsigned)h0 | ((unsigned)h1 << 16);
            lo[i] = (unsigned)f2bf(v0 - bf2f(h0)) | ((unsigned)f2bf(v1 - bf2f(h1)) << 16);
        }
        *(uint4*)&WfragQ_hi[(size_t)t2 * 8] = *(const uint4*)hi;
        *(uint4*)&WfragQ_lo[(size_t)t2 * 8] = *(const uint4*)lo;
    }
}

// ---------------- Kernel 1: coarse LN + gate + MFMA GEMM (as R9) -----------
#define AP 520
__global__ __launch_bounds__(512) void k_coarse_fused(
    const float* __restrict__ coarse,
    const float* __restrict__ ln_g, const float* __restrict__ ln_b,
    const float* __restrict__ w_gate, const float* __restrict__ b_gate,
    const unsigned short* __restrict__ WfragC_hi,
    const unsigned short* __restrict__ WfragC_lo,
    const float* __restrict__ b_qc, const float* __restrict__ b_k,
    const float* __restrict__ b_v,
    float* __restrict__ gate_o, float* __restrict__ qc_o,
    unsigned* __restrict__ key_pk, unsigned short* __restrict__ val_b)
{
    __shared__ unsigned short Ah[32 * AP];
    __shared__ unsigned short Al[32 * AP];
    const int tid = threadIdx.x;
    const int lane = tid & 63, wave = tid >> 6;
    const int ci0 = blockIdx.x << 5;

    for (int pp = 0; pp < 4; ++pp) {
        const int p = (wave << 2) + pp;
        const float* src = coarse + (size_t)(ci0 + p) * 512;
        const int c0 = lane * 4, c1 = 256 + lane * 4;
        const float4 x0 = ntload4(src + c0);
        const float4 x1 = ntload4(src + c1);
        float s = (x0.x + x0.y) + (x0.z + x0.w) + (x1.x + x1.y) + (x1.z + x1.w);
        float sq = x0.x*x0.x + x0.y*x0.y + x0.z*x0.z + x0.w*x0.w
                 + x1.x*x1.x + x1.y*x1.y + x1.z*x1.z + x1.w*x1.w;
        s = wave_sum(s); sq = wave_sum(sq);
        const float mean = s * (1.0f / 512.0f);
        const float var  = sq * (1.0f / 512.0f) - mean * mean;
        const float inv  = rsqrtf(var + 1e-3f);
        const float4 g0 = *(const float4*)(ln_g + c0), g1 = *(const float4*)(ln_g + c1);
        const float4 h0 = *(const float4*)(ln_b + c0), h1 = *(const float4*)(ln_b + c1);
        float y[8];
        y[0] = (x0.x - mean) * inv * g0.x + h0.x;
        y[1] = (x0.y - mean) * inv * g0.y + h0.y;
        y[2] = (x0.z - mean) * inv * g0.z + h0.z;
        y[3] = (x0.w - mean) * inv * g0.w + h0.w;
        y[4] = (x1.x - mean) * inv * g1.x + h1.x;
        y[5] = (x1.y - mean) * inv * g1.y + h1.y;
        y[6] = (x1.z - mean) * inv * g1.z + h1.z;
        y[7] = (x1.w - mean) * inv * g1.w + h1.w;
        unsigned short* ah = Ah + p * AP;
        unsigned short* al = Al + p * AP;
#pragma unroll
        for (int j = 0; j < 8; ++j) {
            const int c = (j < 4) ? (c0 + j) : (c1 + j - 4);
            const unsigned short h = f2bf(y[j]);
            ah[c] = h;
            al[c] = f2bf(y[j] - bf2f(h));
        }
        const float4 wg0 = *(const float4*)(w_gate + c0), wg1 = *(const float4*)(w_gate + c1);
        float gd = y[0]*wg0.x + y[1]*wg0.y + y[2]*wg0.z + y[3]*wg0.w
                 + y[4]*wg1.x + y[5]*wg1.y + y[6]*wg1.z + y[7]*wg1.w;
        gd = wave_sum(gd);
        if (lane == 0) gate_o[ci0 + p] = 1.0f / (1.0f + __expf(-(gd + b_gate[0])));
    }
    __syncthreads();

    const int lrow = lane & 15, m16 = lane & 15, lk = (lane >> 4) * 8;
    f32x4 acc_s[2], acc_v[2][2];
#pragma unroll
    for (int i = 0; i < 2; ++i) {
        acc_s[i] = (f32x4){0.f, 0.f, 0.f, 0.f};
        acc_v[i][0] = (f32x4){0.f, 0.f, 0.f, 0.f};
        acc_v[i][1] = (f32x4){0.f, 0.f, 0.f, 0.f};
    }

    const unsigned short* Fs_h = WfragC_hi + ((size_t)(wave * 16) * 64 + lane) * 8;
    const unsigned short* Fs_l = WfragC_lo + ((size_t)(wave * 16) * 64 + lane) * 8;
    const unsigned short* Fv0  = WfragC_hi + ((size_t)((8 + 2*wave) * 16) * 64 + lane) * 8;
    const unsigned short* Fv1  = WfragC_hi + ((size_t)((9 + 2*wave) * 16) * 64 + lane) * 8;
    const int KSTEP = 64 * 8;

    bf16x8 pbh[4], pbl[4], pv0[4], pv1[4];
#pragma unroll
    for (int i = 0; i < 4; ++i) {
        pbh[i] = *(const bf16x8*)(Fs_h + i * KSTEP);
        pbl[i] = *(const bf16x8*)(Fs_l + i * KSTEP);
        pv0[i] = *(const bf16x8*)(Fv0 + i * KSTEP);
        pv1[i] = *(const bf16x8*)(Fv1 + i * KSTEP);
    }

#pragma unroll
    for (int kk = 0; kk < 16; ++kk) {
        const int cur = kk & 3;
        const bf16x8 bh = pbh[cur], bl = pbl[cur], v0 = pv0[cur], v1 = pv1[cur];
        if (kk < 12) {
            pbh[cur] = *(const bf16x8*)(Fs_h + (kk + 4) * KSTEP);
            pbl[cur] = *(const bf16x8*)(Fs_l + (kk + 4) * KSTEP);
            pv0[cur] = *(const bf16x8*)(Fv0 + (kk + 4) * KSTEP);
            pv1[cur] = *(const bf16x8*)(Fv1 + (kk + 4) * KSTEP);
        }
        bf16x8 ah[2], alo[2];
#pragma unroll
        for (int mf = 0; mf < 2; ++mf) {
            ah[mf]  = *(const bf16x8*)&Ah[(mf * 16 + lrow) * AP + kk * 32 + lk];
            alo[mf] = *(const bf16x8*)&Al[(mf * 16 + lrow) * AP + kk * 32 + lk];
        }
#pragma unroll
        for (int mf = 0; mf < 2; ++mf) {
            acc_s[mf] = __builtin_amdgcn_mfma_f32_16x16x32_bf16(ah[mf],  bh, acc_s[mf], 0, 0, 0);
            acc_s[mf] = __builtin_amdgcn_mfma_f32_16x16x32_bf16(alo[mf], bh, acc_s[mf], 0, 0, 0);
            acc_s[mf] = __builtin_amdgcn_mfma_f32_16x16x32_bf16(ah[mf],  bl, acc_s[mf], 0, 0, 0);
            acc_v[mf][0] = __builtin_amdgcn_mfma_f32_16x16x32_bf16(ah[mf], v0, acc_v[mf][0], 0, 0, 0);
            acc_v[mf][1] = __builtin_amdgcn_mfma_f32_16x16x32_bf16(ah[mf], v1, acc_v[mf][1], 0, 0, 0);
        }
    }

    const int rbase = (lane >> 4) * 4;
    const int ns = wave * 16 + m16;
#pragma unroll
    for (int mf = 0; mf < 2; ++mf) {
#pragma unroll
        for (int r = 0; r < 4; ++r) {
            const int m = mf * 16 + rbase + r;
            const int ci = ci0 + m;
            const float vs = acc_s[mf][r];
            if (ns < 64) qc_o[(size_t)ci * 64 + ns] = vs + b_qc[ns];
            else         key_pk[(size_t)ci * 64 + ns - 64] = packsplit(vs + b_k[ns - 64]);
#pragma unroll
            for (int vv = 0; vv < 2; ++vv) {
                const int ch = wave * 32 + vv * 16 + m16;
                val_b[(size_t)ci * 256 + ch] = f2bf(acc_v[mf][vv][r] + b_v[ch]);
            }
        }
    }
}

// ---------------- Kernel 2: fine LN + qf + gating -> QF frag-linear --------
// QF layout: [b][fy][fx>>3] groups of 512 u32: [kf][g4][px(fx&7)][j 0..7]
#define QP 264
__global__ __launch_bounds__(256) void k_query_fused(
    const float* __restrict__ fine,
    const float* __restrict__ ln_g, const float* __restrict__ ln_b,
    const unsigned short* __restrict__ WfragQ_hi,
    const unsigned short* __restrict__ WfragQ_lo,
    const float* __restrict__ b_qf,
    const float* __restrict__ gate_i, const float* __restrict__ qc_i,
    unsigned* __restrict__ QF)
{
    __shared__ unsigned short Ah[32 * QP];
    __shared__ unsigned short Al[32 * QP];
    const int tid = threadIdx.x;
    const int lane = tid & 63, wave = tid >> 6;
    const int fp0 = blockIdx.x << 5;

    for (int pp = 0; pp < 8; ++pp) {
        const int p = (wave << 3) + pp;
        const float* src = fine + (size_t)(fp0 + p) * 256;
        const int c0 = lane * 4;
        const float4 x = ntload4(src + c0);
        float s = (x.x + x.y) + (x.z + x.w);
        float sq = x.x*x.x + x.y*x.y + x.z*x.z + x.w*x.w;
        s = wave_sum(s); sq = wave_sum(sq);
        const float mean = s * (1.0f / 256.0f);
        const float var  = sq * (1.0f / 256.0f) - mean * mean;
        const float inv  = rsqrtf(var + 1e-3f);
        const float4 g = *(const float4*)(ln_g + c0);
        const float4 h = *(const float4*)(ln_b + c0);
        float y[4];
        y[0] = (x.x - mean) * inv * g.x + h.x;
        y[1] = (x.y - mean) * inv * g.y + h.y;
        y[2] = (x.z - mean) * inv * g.z + h.z;
        y[3] = (x.w - mean) * inv * g.w + h.w;
        unsigned short* ah = Ah + p * QP;
        unsigned short* al = Al + p * QP;
#pragma unroll
        for (int j = 0; j < 4; ++j) {
            const unsigned short hh = f2bf(y[j]);
            ah[c0 + j] = hh;
            al[c0 + j] = f2bf(y[j] - bf2f(hh));
        }
    }
    __syncthreads();

    const int lrow = lane & 15, lk = (lane >> 4) * 8;
    f32x4 acc[2];
    acc[0] = (f32x4){0.f, 0.f, 0.f, 0.f};
    acc[1] = (f32x4){0.f, 0.f, 0.f, 0.f};

    const unsigned short* Fh = WfragQ_hi + ((size_t)(wave * 8) * 64 + lane) * 8;
    const unsigned short* Fl = WfragQ_lo + ((size_t)(wave * 8) * 64 + lane) * 8;
    const int KSTEP = 64 * 8;
    bf16x8 pbh[4], pbl[4];
#pragma unroll
    for (int i = 0; i < 4; ++i) {
        pbh[i] = *(const bf16x8*)(Fh + i * KSTEP);
        pbl[i] = *(const bf16x8*)(Fl + i * KSTEP);
    }

#pragma unroll
    for (int kk = 0; kk < 8; ++kk) {
        const int cur = kk & 3;
        const bf16x8 bh = pbh[cur], bl = pbl[cur];
        if (kk < 4) {
            pbh[cur] = *(const bf16x8*)(Fh + (kk + 4) * KSTEP);
            pbl[cur] = *(const bf16x8*)(Fl + (kk + 4) * KSTEP);
        }
#pragma unroll
        for (int mf = 0; mf < 2; ++mf) {
            const bf16x8 ah = *(const bf16x8*)&Ah[(mf * 16 + lrow) * QP + kk * 32 + lk];
            const bf16x8 al = *(const bf16x8*)&Al[(mf * 16 + lrow) * QP + kk * 32 + lk];
            acc[mf] = __builtin_amdgcn_mfma_f32_16x16x32_bf16(ah, bh, acc[mf], 0, 0, 0);
            acc[mf] = __builtin_amdgcn_mfma_f32_16x16x32_bf16(al, bh, acc[mf], 0, 0, 0);
            acc[mf] = __builtin_amdgcn_mfma_f32_16x16x32_bf16(ah, bl, acc[mf], 0, 0, 0);
        }
    }

    const int n = wave * 16 + (lane & 15);
    const float bias = b_qf[n];
    const int kfq = n >> 5, g4q = (n >> 3) & 3, jq = n & 7;
    const int rbase = (lane >> 4) * 4;
#pragma unroll
    for (int mf = 0; mf < 2; ++mf) {
#pragma unroll
        for (int r = 0; r < 4; ++r) {
            const int m = mf * 16 + rbase + r;
            const int fp = fp0 + m;
            const int wx = fp & 127, h = (fp >> 7) & 127, b2 = fp >> 14;
            const int ci = ((b2 << 6) + (h >> 1)) * 64 + (wx >> 1);
            const float gt = gate_i[ci];
            const float qcv = qc_i[(size_t)ci * 64 + n];
            const size_t dst = ((size_t)((b2 * 128 + h) * 16 + (wx >> 3)) * 512)
                             + kfq * 256 + g4q * 64 + (wx & 7) * 8 + jq;
            QF[dst] = packsplit((acc[mf][r] + bias) * gt + qcv * (1.0f - gt));
        }
    }
}

// ---------------- Kernel 3: MFMA 5x5 local attention -----------------------
// LDS (u16 idx): K_HI [0,4096) | K_LO [4096,8192) (ATT overlays after QK) |
//                VT [8192,24576) 256ch x 64pos XOR-swizzled.  48 KB total.
#define LDS_K_HI 0
#define LDS_K_LO 4096
#define LDS_ATT  4096
#define LDS_VT   8192
__global__ __launch_bounds__(256) void k_attn_mfma(
    const unsigned* __restrict__ QF, const unsigned* __restrict__ key_pk,
    const unsigned short* __restrict__ val_b, float* __restrict__ out)
{
    __shared__ unsigned short LDS[24576];
    const int tid = threadIdx.x;
    const int lane = tid & 63, wave = tid >> 6;
    const int m16 = lane & 15, g4 = lane >> 4;
    const int blk = blockIdx.x;
    const int bx = blk & 15, by = (blk >> 4) & 15, bb = blk >> 8;
    const int cy0 = by << 2, cx0 = bx << 2;

    // ---- stage K coalesced: instr i covers 4 taps x 256B ----
#pragma unroll
    for (int i = 0; i < 4; ++i) {
        const int t = wave * 16 + i * 4 + g4;
        const int cy = cy0 - 2 + (t >> 3), cx = cx0 - 2 + (t & 7);
        uint4 kw = make_uint4(0u, 0u, 0u, 0u);
        if ((unsigned)cy < 64u && (unsigned)cx < 64u)
            kw = *(const uint4*)(key_pk + ((size_t)(((bb << 6) + cy) << 6) + cx) * 64 + m16 * 4);
        unsigned hi[2], lo[2];
        hi[0] = (kw.x & 0xffffu) | ((kw.y & 0xffffu) << 16);
        hi[1] = (kw.z & 0xffffu) | ((kw.w & 0xffffu) << 16);
        lo[0] = (kw.x >> 16) | (kw.y & 0xffff0000u);
        lo[1] = (kw.z >> 16) | (kw.w & 0xffff0000u);
        const int a = t * 64 + (((m16 >> 1) ^ (t & 7)) << 3) + (m16 & 1) * 4;
        *(uint2*)&LDS[LDS_K_HI + a] = *(const uint2*)hi;
        *(uint2*)&LDS[LDS_K_LO + a] = *(const uint2*)lo;
    }

    // ---- stage V coalesced: half-wave reads one pixel's 512B; XOR'd VT ----
    {
        const int lh = lane & 31, half = lane >> 5;
        const int sw = (lh & 7) << 3;               // = ((ch>>3)&7)<<3 for ch=8*lh+j
#pragma unroll
        for (int st = 0; st < 8; ++st) {
            const int p = wave * 16 + st * 2 + half;
            const int cy = cy0 - 2 + (p >> 3), cx = cx0 - 2 + (p & 7);
            uint4 vw = make_uint4(0u, 0u, 0u, 0u);
            if ((unsigned)cy < 64u && (unsigned)cx < 64u)
                vw = *(const uint4*)(val_b + ((size_t)(((bb << 6) + cy) << 6) + cx) * 256 + lh * 8);
            const unsigned short* vu = (const unsigned short*)&vw;
            const int pp2 = p ^ sw;
            const int chb = lh * 8;
#pragma unroll
            for (int j = 0; j < 8; ++j)
                LDS[LDS_VT + (chb + j) * 64 + pp2] = vu[j];
        }
    }

    // ---- Q frags from frag-linear QF (coalesced 2x1KB per instr) ----
    const int fy0 = (by << 3) + (wave << 1);
    bf16x8 qh[2], ql[2];
    {
        const size_t grp = ((size_t)((bb * 128 + fy0 + (m16 >> 3)) * 16 + bx)) * 512;
#pragma unroll
        for (int kf = 0; kf < 2; ++kf) {
            const unsigned* qg = QF + grp + kf * 256 + g4 * 64 + (m16 & 7) * 8;
            unsigned w[8];
            *(uint4*)&w[0] = *(const uint4*)qg;
            *(uint4*)&w[4] = *(const uint4*)(qg + 4);
            union { unsigned u[4]; bf16x8 b; } uh, ul;
#pragma unroll
            for (int i = 0; i < 4; ++i) {
                const unsigned w0 = w[2 * i], w1 = w[2 * i + 1];
                uh.u[i] = (w0 & 0xffffu) | ((w1 & 0xffffu) << 16);
                ul.u[i] = (w0 >> 16) | (w1 & 0xffff0000u);
            }
            qh[kf] = uh.b; ql[kf] = ul.b;
        }
    }

    __syncthreads();

    // ---- scores: M=16px, N=48 taps, K=64, split-bf16 ----
    f32x4 sc[3];
#pragma unroll
    for (int nf = 0; nf < 3; ++nf) sc[nf] = (f32x4){0.f, 0.f, 0.f, 0.f};
#pragma unroll
    for (int nf = 0; nf < 3; ++nf) {
        const int row = 8 * wave + nf * 16 + m16;
#pragma unroll
        for (int kf = 0; kf < 2; ++kf) {
            const int G = kf * 4 + g4;
            const int a = row * 64 + ((G ^ (m16 & 7)) * 8);
            const bf16x8 bh = *(const bf16x8*)&LDS[LDS_K_HI + a];
            const bf16x8 bl = *(const bf16x8*)&LDS[LDS_K_LO + a];
            sc[nf] = __builtin_amdgcn_mfma_f32_16x16x32_bf16(qh[kf], bh, sc[nf], 0, 0, 0);
            sc[nf] = __builtin_amdgcn_mfma_f32_16x16x32_bf16(ql[kf], bh, sc[nf], 0, 0, 0);
            sc[nf] = __builtin_amdgcn_mfma_f32_16x16x32_bf16(qh[kf], bl, sc[nf], 0, 0, 0);
        }
    }

    // ---- mask + softmax (px rows live as 4g4+r, tap cols as m16) ----
    float e[3][4];
    float rinv[4];
#pragma unroll
    for (int r = 0; r < 4; ++r) {
        const int m = 4 * g4 + r;
        const int j = (m & 7) >> 1;
        float mr = -1e30f;
#pragma unroll
        for (int nf = 0; nf < 3; ++nf) {
            const int tf = nf * 16 + m16;
            const int tc = tf & 7;
            const bool c = (tf < 40) && (tc >= j) && (tc <= j + 4);
            e[nf][r] = c ? sc[nf][r] : -1e30f;
            mr = fmaxf(mr, e[nf][r]);
        }
#pragma unroll
        for (int msk = 1; msk < 16; msk <<= 1) mr = fmaxf(mr, __shfl_xor(mr, msk, 64));
        float s = 0.f;
#pragma unroll
        for (int nf = 0; nf < 3; ++nf) {
            const float ev = (e[nf][r] > -1e29f) ? __expf(e[nf][r] - mr) : 0.f;
            e[nf][r] = ev; s += ev;
        }
#pragma unroll
        for (int msk = 1; msk < 16; msk <<= 1) s += __shfl_xor(s, msk, 64);
        rinv[r] = 1.0f / s;
    }

    __syncthreads();   // all K_LO reads done -> ATT may overlay

    // ---- zero own att rows (wave-private) then write att bf16 swizzled ----
    {
        const uint4 z = {0u, 0u, 0u, 0u};
        *(uint4*)&LDS[LDS_ATT + wave * 1024 + lane * 16] = z;
        *(uint4*)&LDS[LDS_ATT + wave * 1024 + lane * 16 + 8] = z;
    }
#pragma unroll
    for (int nf = 0; nf < 3; ++nf) {
        const int t = 8 * wave + nf * 16 + m16;
        if (t < 64) {
#pragma unroll
            for (int r = 0; r < 4; ++r) {
                const int prow = wave * 16 + 4 * g4 + r;
                const int a = prow * 64 + (((t >> 3) ^ (prow & 7)) * 8) + (t & 7);
                LDS[LDS_ATT + a] = f2bf(e[nf][r] * rinv[r]);
            }
        }
    }

    // ---- PV (swapped): D[ch][px] = mfma(A=V^T, B=att) ----
    bf16x8 af[2];
#pragma unroll
    for (int kf = 0; kf < 2; ++kf) {
        const int row = wave * 16 + m16;
        const int G = kf * 4 + g4;
        af[kf] = *(const bf16x8*)&LDS[LDS_ATT + row * 64 + ((G ^ (m16 & 7)) * 8)];
    }
    f32x4 ao[16];
#pragma unroll
    for (int nf = 0; nf < 16; ++nf) ao[nf] = (f32x4){0.f, 0.f, 0.f, 0.f};
#pragma unroll
    for (int nf = 0; nf < 16; ++nf) {
        const int ch = nf * 16 + m16;
        const int sr = ((ch >> 3) & 7) << 3;
#pragma unroll
        for (int kf = 0; kf < 2; ++kf) {
            const bf16x8 bv = *(const bf16x8*)&LDS[LDS_VT + ch * 64 + ((kf * 32 + g4 * 8) ^ sr)];
            ao[nf] = __builtin_amdgcn_mfma_f32_16x16x32_bf16(bv, af[kf], ao[nf], 0, 0, 0);
        }
    }

    // ---- store: lane holds 4 consecutive ch -> float4 ----
    {
        const int fy = fy0 + (m16 >> 3), fx = (bx << 3) + (m16 & 7);
        float* op = out + ((size_t)(((bb << 7) + fy) << 7) + fx) * 256 + g4 * 4;
#pragma unroll
        for (int nf = 0; nf < 16; ++nf)
            *(float4*)(op + nf * 16) = make_float4(ao[nf][0], ao[nf][1], ao[nf][2], ao[nf][3]);
    }
}

// ---------------- launch ----------------
extern "C" void kernel_launch(void* const* d_in, const int* in_sizes, int n_in,
                              void* d_out, int out_size, void* d_ws, size_t ws_size,
                              hipStream_t stream)
{
    const float* fine   = (const float*)d_in[0];
    const float* coarse = (const float*)d_in[1];
    const float* ln_f_g = (const float*)d_in[2];
    const float* ln_f_b = (const float*)d_in[3];
    const float* ln_c_g = (const float*)d_in[4];
    const float* ln_c_b = (const float*)d_in[5];
    const float* w_gate = (const float*)d_in[6];
    const float* b_gate = (const float*)d_in[7];
    const float* w_qf   = (const float*)d_in[8];
    const float* b_qf   = (const float*)d_in[9];
    const float* w_qc   = (const float*)d_in[10];
    const float* b_qc   = (const float*)d_in[11];
    const float* w_k    = (const float*)d_in[12];
    const float* b_k    = (const float*)d_in[13];
    const float* w_v    = (const float*)d_in[14];
    const float* b_v    = (const float*)d_in[15];
    float* out = (float*)d_out;

    float* ws   = (float*)d_ws;
    float* gate = ws;                                           // 16384 f32
    float* qc   = gate + 16384;                                 // 16384*64 f32
    unsigned* key_pk = (unsigned*)(qc + (size_t)16384 * 64);    // 16384*64 u32
    unsigned short* val_b = (unsigned short*)(key_pk + (size_t)16384 * 64); // 16384*256 u16
    unsigned* QF = (unsigned*)(val_b + (size_t)16384 * 256);                // 4*128*16*512 u32
    unsigned short* WfragC_hi = (unsigned short*)(QF + (size_t)4 * 128 * 16 * 512);
    unsigned short* WfragC_lo = WfragC_hi + (size_t)24576 * 8;
    unsigned short* WfragQ_hi = WfragC_lo + (size_t)8192 * 8;
    unsigned short* WfragQ_lo = WfragQ_hi + (size_t)2048 * 8;

    k_wconv<<<104, 256, 0, stream>>>(w_qc, w_k, w_v, w_qf,
                                     WfragC_hi, WfragC_lo, WfragQ_hi, WfragQ_lo);
    k_coarse_fused<<<512, 512, 0, stream>>>(coarse, ln_c_g, ln_c_b, w_gate, b_gate,
                                            WfragC_hi, WfragC_lo, b_qc, b_k, b_v,
                                            gate, qc, key_pk, val_b);
    k_query_fused<<<2048, 256, 0, stream>>>(fine, ln_f_g, ln_f_b, WfragQ_hi, WfragQ_lo, b_qf,
                                            gate, qc, QF);
    k_attn_mfma<<<1024, 256, 0, stream>>>(QF, key_pk, val_b, out);
}

// Round 13
// 87.405 us; speedup vs baseline: 1.1708x; 1.0003x over previous
//
#include <hip/hip_runtime.h>
#include <math.h>

typedef __bf16 bf16x8 __attribute__((ext_vector_type(8)));
typedef float  f32x4  __attribute__((ext_vector_type(4)));
typedef float  vf4    __attribute__((ext_vector_type(4)));

__device__ __forceinline__ float wave_sum(float v) {
#pragma unroll
    for (int m = 1; m < 64; m <<= 1) v += __shfl_xor(v, m, 64);
    return v;
}

__device__ __forceinline__ unsigned short f2bf(float f) {
    union { float f; unsigned int u; } x; x.f = f;
    unsigned int u = x.u;
    u += 0x7fffu + ((u >> 16) & 1u);   // round-to-nearest-even
    return (unsigned short)(u >> 16);
}
__device__ __forceinline__ float bf2f(unsigned short h) {
    union { unsigned int u; float f; } x; x.u = ((unsigned int)h) << 16;
    return x.f;
}
__device__ __forceinline__ unsigned packsplit(float v) {
    const unsigned short h = f2bf(v);
    const unsigned short l = f2bf(v - bf2f(h));
    return (unsigned)h | ((unsigned)l << 16);
}
__device__ __forceinline__ float4 ntload4(const float* p) {
    const vf4 v = __builtin_nontemporal_load((const vf4*)p);
    return make_float4(v.x, v.y, v.z, v.w);
}

// ------- weight convert to MFMA fragment-linear layout (unchanged) ---------
__global__ __launch_bounds__(256) void k_wconv(
    const float* __restrict__ w_qc, const float* __restrict__ w_k,
    const float* __restrict__ w_v, const float* __restrict__ w_qf,
    unsigned short* __restrict__ WfragC_hi, unsigned short* __restrict__ WfragC_lo,
    unsigned short* __restrict__ WfragQ_hi, unsigned short* __restrict__ WfragQ_lo)
{
    const int t = blockIdx.x * 256 + threadIdx.x;
    if (t < 24576) {
        const int lane = t & 63, kk = (t >> 6) & 15, nf = t >> 10;
        const int n  = nf * 16 + (lane & 15);
        const int k0 = kk * 32 + (lane >> 4) * 8;
        const float* src; int col, w;
        if (n < 64)       { src = w_qc; col = n;       w = 64;  }
        else if (n < 128) { src = w_k;  col = n - 64;  w = 64;  }
        else              { src = w_v;  col = n - 128; w = 256; }
        unsigned hi[4], lo[4];
#pragma unroll
        for (int i = 0; i < 4; ++i) {
            const float v0 = src[(size_t)(k0 + 2*i)     * w + col];
            const float v1 = src[(size_t)(k0 + 2*i + 1) * w + col];
            const unsigned short h0 = f2bf(v0), h1 = f2bf(v1);
            hi[i] = (unsigned)h0 | ((unsigned)h1 << 16);
            lo[i] = (unsigned)f2bf(v0 - bf2f(h0)) | ((unsigned)f2bf(v1 - bf2f(h1)) << 16);
        }
        *(uint4*)&WfragC_hi[(size_t)t * 8] = *(const uint4*)hi;
        if (nf < 8) *(uint4*)&WfragC_lo[(size_t)t * 8] = *(const uint4*)lo;
    } else if (t < 24576 + 2048) {
        const int t2 = t - 24576;
        const int lane = t2 & 63, kk = (t2 >> 6) & 7, nf = t2 >> 9;
        const int n  = nf * 16 + (lane & 15);
        const int k0 = kk * 32 + (lane >> 4) * 8;
        unsigned hi[4], lo[4];
#pragma unroll
        for (int i = 0; i < 4; ++i) {
            const float v0 = w_qf[(size_t)(k0 + 2*i)     * 64 + n];
            const float v1 = w_qf[(size_t)(k0 + 2*i + 1) * 64 + n];
            const unsigned short h0 = f2bf(v0), h1 = f2bf(v1);
            hi[i] = (unsigned)h0 | ((unsigned)h1 << 16);
            lo[i] = (unsigned)f2bf(v0 - bf2f(h0)) | ((unsigned)f2bf(v1 - bf2f(h1)) << 16);
        }
        *(uint4*)&WfragQ_hi[(size_t)t2 * 8] = *(const uint4*)hi;
        *(uint4*)&WfragQ_lo[(size_t)t2 * 8] = *(const uint4*)lo;
    }
}

// ---------------- Kernel 1: coarse LN + gate + MFMA GEMM (as R9) -----------
#define AP 520
__global__ __launch_bounds__(512) void k_coarse_fused(
    const float* __restrict__ coarse,
    const float* __restrict__ ln_g, const float* __restrict__ ln_b,
    const float* __restrict__ w_gate, const float* __restrict__ b_gate,
    const unsigned short* __restrict__ WfragC_hi,
    const unsigned short* __restrict__ WfragC_lo,
    const float* __restrict__ b_qc, const float* __restrict__ b_k,
    const float* __restrict__ b_v,
    float* __restrict__ gate_o, float* __restrict__ qc_o,
    unsigned* __restrict__ key_pk, unsigned short* __restrict__ val_b)
{
    __shared__ unsigned short Ah[32 * AP];
    __shared__ unsigned short Al[32 * AP];
    const int tid = threadIdx.x;
    const int lane = tid & 63, wave = tid >> 6;
    const int ci0 = blockIdx.x << 5;

    for (int pp = 0; pp < 4; ++pp) {
        const int p = (wave << 2) + pp;
        const float* src = coarse + (size_t)(ci0 + p) * 512;
        const int c0 = lane * 4, c1 = 256 + lane * 4;
        const float4 x0 = ntload4(src + c0);
        const float4 x1 = ntload4(src + c1);
        float s = (x0.x + x0.y) + (x0.z + x0.w) + (x1.x + x1.y) + (x1.z + x1.w);
        float sq = x0.x*x0.x + x0.y*x0.y + x0.z*x0.z + x0.w*x0.w
                 + x1.x*x1.x + x1.y*x1.y + x1.z*x1.z + x1.w*x1.w;
        s = wave_sum(s); sq = wave_sum(sq);
        const float mean = s * (1.0f / 512.0f);
        const float var  = sq * (1.0f / 512.0f) - mean * mean;
        const float inv  = rsqrtf(var + 1e-3f);
        const float4 g0 = *(const float4*)(ln_g + c0), g1 = *(const float4*)(ln_g + c1);
        const float4 h0 = *(const float4*)(ln_b + c0), h1 = *(const float4*)(ln_b + c1);
        float y[8];
        y[0] = (x0.x - mean) * inv * g0.x + h0.x;
        y[1] = (x0.y - mean) * inv * g0.y + h0.y;
        y[2] = (x0.z - mean) * inv * g0.z + h0.z;
        y[3] = (x0.w - mean) * inv * g0.w + h0.w;
        y[4] = (x1.x - mean) * inv * g1.x + h1.x;
        y[5] = (x1.y - mean) * inv * g1.y + h1.y;
        y[6] = (x1.z - mean) * inv * g1.z + h1.z;
        y[7] = (x1.w - mean) * inv * g1.w + h1.w;
        unsigned short* ah = Ah + p * AP;
        unsigned short* al = Al + p * AP;
#pragma unroll
        for (int j = 0; j < 8; ++j) {
            const int c = (j < 4) ? (c0 + j) : (c1 + j - 4);
            const unsigned short h = f2bf(y[j]);
            ah[c] = h;
            al[c] = f2bf(y[j] - bf2f(h));
        }
        const float4 wg0 = *(const float4*)(w_gate + c0), wg1 = *(const float4*)(w_gate + c1);
        float gd = y[0]*wg0.x + y[1]*wg0.y + y[2]*wg0.z + y[3]*wg0.w
                 + y[4]*wg1.x + y[5]*wg1.y + y[6]*wg1.z + y[7]*wg1.w;
        gd = wave_sum(gd);
        if (lane == 0) gate_o[ci0 + p] = 1.0f / (1.0f + __expf(-(gd + b_gate[0])));
    }
    __syncthreads();

    const int lrow = lane & 15, m16 = lane & 15, lk = (lane >> 4) * 8;
    f32x4 acc_s[2], acc_v[2][2];
#pragma unroll
    for (int i = 0; i < 2; ++i) {
        acc_s[i] = (f32x4){0.f, 0.f, 0.f, 0.f};
        acc_v[i][0] = (f32x4){0.f, 0.f, 0.f, 0.f};
        acc_v[i][1] = (f32x4){0.f, 0.f, 0.f, 0.f};
    }

    const unsigned short* Fs_h = WfragC_hi + ((size_t)(wave * 16) * 64 + lane) * 8;
    const unsigned short* Fs_l = WfragC_lo + ((size_t)(wave * 16) * 64 + lane) * 8;
    const unsigned short* Fv0  = WfragC_hi + ((size_t)((8 + 2*wave) * 16) * 64 + lane) * 8;
    const unsigned short* Fv1  = WfragC_hi + ((size_t)((9 + 2*wave) * 16) * 64 + lane) * 8;
    const int KSTEP = 64 * 8;

    bf16x8 pbh[4], pbl[4], pv0[4], pv1[4];
#pragma unroll
    for (int i = 0; i < 4; ++i) {
        pbh[i] = *(const bf16x8*)(Fs_h + i * KSTEP);
        pbl[i] = *(const bf16x8*)(Fs_l + i * KSTEP);
        pv0[i] = *(const bf16x8*)(Fv0 + i * KSTEP);
        pv1[i] = *(const bf16x8*)(Fv1 + i * KSTEP);
    }

#pragma unroll
    for (int kk = 0; kk < 16; ++kk) {
        const int cur = kk & 3;
        const bf16x8 bh = pbh[cur], bl = pbl[cur], v0 = pv0[cur], v1 = pv1[cur];
        if (kk < 12) {
            pbh[cur] = *(const bf16x8*)(Fs_h + (kk + 4) * KSTEP);
            pbl[cur] = *(const bf16x8*)(Fs_l + (kk + 4) * KSTEP);
            pv0[cur] = *(const bf16x8*)(Fv0 + (kk + 4) * KSTEP);
            pv1[cur] = *(const bf16x8*)(Fv1 + (kk + 4) * KSTEP);
        }
        bf16x8 ah[2], alo[2];
#pragma unroll
        for (int mf = 0; mf < 2; ++mf) {
            ah[mf]  = *(const bf16x8*)&Ah[(mf * 16 + lrow) * AP + kk * 32 + lk];
            alo[mf] = *(const bf16x8*)&Al[(mf * 16 + lrow) * AP + kk * 32 + lk];
        }
#pragma unroll
        for (int mf = 0; mf < 2; ++mf) {
            acc_s[mf] = __builtin_amdgcn_mfma_f32_16x16x32_bf16(ah[mf],  bh, acc_s[mf], 0, 0, 0);
            acc_s[mf] = __builtin_amdgcn_mfma_f32_16x16x32_bf16(alo[mf], bh, acc_s[mf], 0, 0, 0);
            acc_s[mf] = __builtin_amdgcn_mfma_f32_16x16x32_bf16(ah[mf],  bl, acc_s[mf], 0, 0, 0);
            acc_v[mf][0] = __builtin_amdgcn_mfma_f32_16x16x32_bf16(ah[mf], v0, acc_v[mf][0], 0, 0, 0);
            acc_v[mf][1] = __builtin_amdgcn_mfma_f32_16x16x32_bf16(ah[mf], v1, acc_v[mf][1], 0, 0, 0);
        }
    }

    const int rbase = (lane >> 4) * 4;
    const int ns = wave * 16 + m16;
#pragma unroll
    for (int mf = 0; mf < 2; ++mf) {
#pragma unroll
        for (int r = 0; r < 4; ++r) {
            const int m = mf * 16 + rbase + r;
            const int ci = ci0 + m;
            const float vs = acc_s[mf][r];
            if (ns < 64) qc_o[(size_t)ci * 64 + ns] = vs + b_qc[ns];
            else         key_pk[(size_t)ci * 64 + ns - 64] = packsplit(vs + b_k[ns - 64]);
#pragma unroll
            for (int vv = 0; vv < 2; ++vv) {
                const int ch = wave * 32 + vv * 16 + m16;
                val_b[(size_t)ci * 256 + ch] = f2bf(acc_v[mf][vv][r] + b_v[ch]);
            }
        }
    }
}

// ---------------- Kernel 2: fine LN + qf + gating -> QF frag-linear --------
// QF layout: [b][fy][fx>>3] groups of 512 u32: [kf][g4][px(fx&7)][j 0..7]
#define QP 264
__global__ __launch_bounds__(256) void k_query_fused(
    const float* __restrict__ fine,
    const float* __restrict__ ln_g, const float* __restrict__ ln_b,
    const unsigned short* __restrict__ WfragQ_hi,
    const unsigned short* __restrict__ WfragQ_lo,
    const float* __restrict__ b_qf,
    const float* __restrict__ gate_i, const float* __restrict__ qc_i,
    unsigned* __restrict__ QF)
{
    __shared__ unsigned short Ah[32 * QP];
    __shared__ unsigned short Al[32 * QP];
    const int tid = threadIdx.x;
    const int lane = tid & 63, wave = tid >> 6;
    const int fp0 = blockIdx.x << 5;

    for (int pp = 0; pp < 8; ++pp) {
        const int p = (wave << 3) + pp;
        const float* src = fine + (size_t)(fp0 + p) * 256;
        const int c0 = lane * 4;
        const float4 x = ntload4(src + c0);
        float s = (x.x + x.y) + (x.z + x.w);
        float sq = x.x*x.x + x.y*x.y + x.z*x.z + x.w*x.w;
        s = wave_sum(s); sq = wave_sum(sq);
        const float mean = s * (1.0f / 256.0f);
        const float var  = sq * (1.0f / 256.0f) - mean * mean;
        const float inv  = rsqrtf(var + 1e-3f);
        const float4 g = *(const float4*)(ln_g + c0);
        const float4 h = *(const float4*)(ln_b + c0);
        float y[4];
        y[0] = (x.x - mean) * inv * g.x + h.x;
        y[1] = (x.y - mean) * inv * g.y + h.y;
        y[2] = (x.z - mean) * inv * g.z + h.z;
        y[3] = (x.w - mean) * inv * g.w + h.w;
        unsigned short* ah = Ah + p * QP;
        unsigned short* al = Al + p * QP;
#pragma unroll
        for (int j = 0; j < 4; ++j) {
            const unsigned short hh = f2bf(y[j]);
            ah[c0 + j] = hh;
            al[c0 + j] = f2bf(y[j] - bf2f(hh));
        }
    }
    __syncthreads();

    const int lrow = lane & 15, lk = (lane >> 4) * 8;
    f32x4 acc[2];
    acc[0] = (f32x4){0.f, 0.f, 0.f, 0.f};
    acc[1] = (f32x4){0.f, 0.f, 0.f, 0.f};

    const unsigned short* Fh = WfragQ_hi + ((size_t)(wave * 8) * 64 + lane) * 8;
    const unsigned short* Fl = WfragQ_lo + ((size_t)(wave * 8) * 64 + lane) * 8;
    const int KSTEP = 64 * 8;
    bf16x8 pbh[4], pbl[4];
#pragma unroll
    for (int i = 0; i < 4; ++i) {
        pbh[i] = *(const bf16x8*)(Fh + i * KSTEP);
        pbl[i] = *(const bf16x8*)(Fl + i * KSTEP);
    }

#pragma unroll
    for (int kk = 0; kk < 8; ++kk) {
        const int cur = kk & 3;
        const bf16x8 bh = pbh[cur], bl = pbl[cur];
        if (kk < 4) {
            pbh[cur] = *(const bf16x8*)(Fh + (kk + 4) * KSTEP);
            pbl[cur] = *(const bf16x8*)(Fl + (kk + 4) * KSTEP);
        }
#pragma unroll
        for (int mf = 0; mf < 2; ++mf) {
            const bf16x8 ah = *(const bf16x8*)&Ah[(mf * 16 + lrow) * QP + kk * 32 + lk];
            const bf16x8 al = *(const bf16x8*)&Al[(mf * 16 + lrow) * QP + kk * 32 + lk];
            acc[mf] = __builtin_amdgcn_mfma_f32_16x16x32_bf16(ah, bh, acc[mf], 0, 0, 0);
            acc[mf] = __builtin_amdgcn_mfma_f32_16x16x32_bf16(al, bh, acc[mf], 0, 0, 0);
            acc[mf] = __builtin_amdgcn_mfma_f32_16x16x32_bf16(ah, bl, acc[mf], 0, 0, 0);
        }
    }

    const int n = wave * 16 + (lane & 15);
    const float bias = b_qf[n];
    const int kfq = n >> 5, g4q = (n >> 3) & 3, jq = n & 7;
    const int rbase = (lane >> 4) * 4;
#pragma unroll
    for (int mf = 0; mf < 2; ++mf) {
#pragma unroll
        for (int r = 0; r < 4; ++r) {
            const int m = mf * 16 + rbase + r;
            const int fp = fp0 + m;
            const int wx = fp & 127, h = (fp >> 7) & 127, b2 = fp >> 14;
            const int ci = ((b2 << 6) + (h >> 1)) * 64 + (wx >> 1);
            const float gt = gate_i[ci];
            const float qcv = qc_i[(size_t)ci * 64 + n];
            const size_t dst = ((size_t)((b2 * 128 + h) * 16 + (wx >> 3)) * 512)
                             + kfq * 256 + g4q * 64 + (wx & 7) * 8 + jq;
            QF[dst] = packsplit((acc[mf][r] + bias) * gt + qcv * (1.0f - gt));
        }
    }
}

// ---------------- Kernel 3: MFMA 5x5 local attention -----------------------
// LDS (u16 idx): K_HI [0,4096) | K_LO [4096,8192) (ATT overlays after QK) |
//                VT [8192,24576) 256ch x 64pos XOR-swizzled.  48 KB total.
#define LDS_K_HI 0
#define LDS_K_LO 4096
#define LDS_ATT  4096
#define LDS_VT   8192
__global__ __launch_bounds__(256) void k_attn_mfma(
    const unsigned* __restrict__ QF, const unsigned* __restrict__ key_pk,
    const unsigned short* __restrict__ val_b, float* __restrict__ out)
{
    __shared__ unsigned short LDS[24576];
    const int tid = threadIdx.x;
    const int lane = tid & 63, wave = tid >> 6;
    const int m16 = lane & 15, g4 = lane >> 4;
    const int blk = blockIdx.x;
    const int bx = blk & 15, by = (blk >> 4) & 15, bb = blk >> 8;
    const int cy0 = by << 2, cx0 = bx << 2;

    // ---- stage K coalesced: instr i covers 4 taps x 256B ----
#pragma unroll
    for (int i = 0; i < 4; ++i) {
        const int t = wave * 16 + i * 4 + g4;
        const int cy = cy0 - 2 + (t >> 3), cx = cx0 - 2 + (t & 7);
        uint4 kw = make_uint4(0u, 0u, 0u, 0u);
        if ((unsigned)cy < 64u && (unsigned)cx < 64u)
            kw = *(const uint4*)(key_pk + ((size_t)(((bb << 6) + cy) << 6) + cx) * 64 + m16 * 4);
        unsigned hi[2], lo[2];
        hi[0] = (kw.x & 0xffffu) | ((kw.y & 0xffffu) << 16);
        hi[1] = (kw.z & 0xffffu) | ((kw.w & 0xffffu) << 16);
        lo[0] = (kw.x >> 16) | (kw.y & 0xffff0000u);
        lo[1] = (kw.z >> 16) | (kw.w & 0xffff0000u);
        const int a = t * 64 + (((m16 >> 1) ^ (t & 7)) << 3) + (m16 & 1) * 4;
        *(uint2*)&LDS[LDS_K_HI + a] = *(const uint2*)hi;
        *(uint2*)&LDS[LDS_K_LO + a] = *(const uint2*)lo;
    }

    // ---- stage V coalesced: half-wave reads one pixel's 512B; XOR'd VT ----
    {
        const int lh = lane & 31, half = lane >> 5;
        const int sw = (lh & 7) << 3;               // = ((ch>>3)&7)<<3 for ch=8*lh+j
#pragma unroll
        for (int st = 0; st < 8; ++st) {
            const int p = wave * 16 + st * 2 + half;
            const int cy = cy0 - 2 + (p >> 3), cx = cx0 - 2 + (p & 7);
            uint4 vw = make_uint4(0u, 0u, 0u, 0u);
            if ((unsigned)cy < 64u && (unsigned)cx < 64u)
                vw = *(const uint4*)(val_b + ((size_t)(((bb << 6) + cy) << 6) + cx) * 256 + lh * 8);
            const unsigned short* vu = (const unsigned short*)&vw;
            const int pp2 = p ^ sw;
            const int chb = lh * 8;
#pragma unroll
            for (int j = 0; j < 8; ++j)
                LDS[LDS_VT + (chb + j) * 64 + pp2] = vu[j];
        }
    }

    // ---- Q frags from frag-linear QF (coalesced 2x1KB per instr) ----
    const int fy0 = (by << 3) + (wave << 1);
    bf16x8 qh[2], ql[2];
    {
        const size_t grp = ((size_t)((bb * 128 + fy0 + (m16 >> 3)) * 16 + bx)) * 512;
#pragma unroll
        for (int kf = 0; kf < 2; ++kf) {
            const unsigned* qg = QF + grp + kf * 256 + g4 * 64 + (m16 & 7) * 8;
            unsigned w[8];
            *(uint4*)&w[0] = *(const uint4*)qg;
            *(uint4*)&w[4] = *(const uint4*)(qg + 4);
            union { unsigned u[4]; bf16x8 b; } uh, ul;
#pragma unroll
            for (int i = 0; i < 4; ++i) {
                const unsigned w0 = w[2 * i], w1 = w[2 * i + 1];
                uh.u[i] = (w0 & 0xffffu) | ((w1 & 0xffffu) << 16);
                ul.u[i] = (w0 >> 16) | (w1 & 0xffff0000u);
            }
            qh[kf] = uh.b; ql[kf] = ul.b;
        }
    }

    __syncthreads();

    // ---- scores: M=16px, N=48 taps, K=64, split-bf16 ----
    f32x4 sc[3];
#pragma unroll
    for (int nf = 0; nf < 3; ++nf) sc[nf] = (f32x4){0.f, 0.f, 0.f, 0.f};
#pragma unroll
    for (int nf = 0; nf < 3; ++nf) {
        const int row = 8 * wave + nf * 16 + m16;
#pragma unroll
        for (int kf = 0; kf < 2; ++kf) {
            const int G = kf * 4 + g4;
            const int a = row * 64 + ((G ^ (m16 & 7)) * 8);
            const bf16x8 bh = *(const bf16x8*)&LDS[LDS_K_HI + a];
            const bf16x8 bl = *(const bf16x8*)&LDS[LDS_K_LO + a];
            sc[nf] = __builtin_amdgcn_mfma_f32_16x16x32_bf16(qh[kf], bh, sc[nf], 0, 0, 0);
            sc[nf] = __builtin_amdgcn_mfma_f32_16x16x32_bf16(ql[kf], bh, sc[nf], 0, 0, 0);
            sc[nf] = __builtin_amdgcn_mfma_f32_16x16x32_bf16(qh[kf], bl, sc[nf], 0, 0, 0);
        }
    }

    // ---- mask + softmax (px rows live as 4g4+r, tap cols as m16) ----
    float e[3][4];
    float rinv[4];
#pragma unroll
    for (int r = 0; r < 4; ++r) {
        const int m = 4 * g4 + r;
        const int j = (m & 7) >> 1;
        float mr = -1e30f;
#pragma unroll
        for (int nf = 0; nf < 3; ++nf) {
            const int tf = nf * 16 + m16;
            const int tc = tf & 7;
            const bool c = (tf < 40) && (tc >= j) && (tc <= j + 4);
            e[nf][r] = c ? sc[nf][r] : -1e30f;
            mr = fmaxf(mr, e[nf][r]);
        }
#pragma unroll
        for (int msk = 1; msk < 16; msk <<= 1) mr = fmaxf(mr, __shfl_xor(mr, msk, 64));
        float s = 0.f;
#pragma unroll
        for (int nf = 0; nf < 3; ++nf) {
            const float ev = (e[nf][r] > -1e29f) ? __expf(e[nf][r] - mr) : 0.f;
            e[nf][r] = ev; s += ev;
        }
#pragma unroll
        for (int msk = 1; msk < 16; msk <<= 1) s += __shfl_xor(s, msk, 64);
        rinv[r] = 1.0f / s;
    }

    __syncthreads();   // all K_LO reads done -> ATT may overlay

    // ---- zero own att rows (wave-private) then write att bf16 swizzled ----
    {
        const uint4 z = {0u, 0u, 0u, 0u};
        *(uint4*)&LDS[LDS_ATT + wave * 1024 + lane * 16] = z;
        *(uint4*)&LDS[LDS_ATT + wave * 1024 + lane * 16 + 8] = z;
    }
#pragma unroll
    for (int nf = 0; nf < 3; ++nf) {
        const int t = 8 * wave + nf * 16 + m16;
        if (t < 64) {
#pragma unroll
            for (int r = 0; r < 4; ++r) {
                const int prow = wave * 16 + 4 * g4 + r;
                const int a = prow * 64 + (((t >> 3) ^ (prow & 7)) * 8) + (t & 7);
                LDS[LDS_ATT + a] = f2bf(e[nf][r] * rinv[r]);
            }
        }
    }

    // ---- PV (swapped): D[ch][px] = mfma(A=V^T, B=att) ----
    bf16x8 af[2];
#pragma unroll
    for (int kf = 0; kf < 2; ++kf) {
        const int row = wave * 16 + m16;
        const int G = kf * 4 + g4;
        af[kf] = *(const bf16x8*)&LDS[LDS_ATT + row * 64 + ((G ^ (m16 & 7)) * 8)];
    }
    f32x4 ao[16];
#pragma unroll
    for (int nf = 0; nf < 16; ++nf) ao[nf] = (f32x4){0.f, 0.f, 0.f, 0.f};
#pragma unroll
    for (int nf = 0; nf < 16; ++nf) {
        const int ch = nf * 16 + m16;
        const int sr = ((ch >> 3) & 7) << 3;
#pragma unroll
        for (int kf = 0; kf < 2; ++kf) {
            const bf16x8 bv = *(const bf16x8*)&LDS[LDS_VT + ch * 64 + ((kf * 32 + g4 * 8) ^ sr)];
            ao[nf] = __builtin_amdgcn_mfma_f32_16x16x32_bf16(bv, af[kf], ao[nf], 0, 0, 0);
        }
    }

    // ---- store: lane holds 4 consecutive ch -> float4 ----
    {
        const int fy = fy0 + (m16 >> 3), fx = (bx << 3) + (m16 & 7);
        float* op = out + ((size_t)(((bb << 7) + fy) << 7) + fx) * 256 + g4 * 4;
#pragma unroll
        for (int nf = 0; nf < 16; ++nf)
            *(float4*)(op + nf * 16) = make_float4(ao[nf][0], ao[nf][1], ao[nf][2], ao[nf][3]);
    }
}

// ---------------- launch ----------------
extern "C" void kernel_launch(void* const* d_in, const int* in_sizes, int n_in,
                              void* d_out, int out_size, void* d_ws, size_t ws_size,
                              hipStream_t stream)
{
    const float* fine   = (const float*)d_in[0];
    const float* coarse = (const float*)d_in[1];
    const float* ln_f_g = (const float*)d_in[2];
    const float* ln_f_b = (const float*)d_in[3];
    const float* ln_c_g = (const float*)d_in[4];
    const float* ln_c_b = (const float*)d_in[5];
    const float* w_gate = (const float*)d_in[6];
    const float* b_gate = (const float*)d_in[7];
    const float* w_qf   = (const float*)d_in[8];
    const float* b_qf   = (const float*)d_in[9];
    const float* w_qc   = (const float*)d_in[10];
    const float* b_qc   = (const float*)d_in[11];
    const float* w_k    = (const float*)d_in[12];
    const float* b_k    = (const float*)d_in[13];
    const float* w_v    = (const float*)d_in[14];
    const float* b_v    = (const float*)d_in[15];
    float* out = (float*)d_out;

    float* ws   = (float*)d_ws;
    float* gate = ws;
    float* qc   = gate + 16384;
    unsigned* key_pk = (unsigned*)(qc + (size_t)16384 * 64);
    unsigned short* val_b = (unsigned short*)(key_pk + (size_t)16384 * 64);
    unsigned* QF = (unsigned*)(val_b + (size_t)16384 * 256);
    unsigned short* WfragC_hi = (unsigned short*)(QF + (size_t)4 * 128 * 16 * 512);
    unsigned short* WfragC_lo = WfragC_hi + (size_t)24576 * 8;
    unsigned short* WfragQ_hi = WfragC_lo + (size_t)8192 * 8;
    unsigned short* WfragQ_lo = WfragQ_hi + (size_t)2048 * 8;

    k_wconv<<<104, 256, 0, stream>>>(w_qc, w_k, w_v, w_qf,
                                     WfragC_hi, WfragC_lo, WfragQ_hi, WfragQ_lo);
    k_coarse_fused<<<512, 512, 0, stream>>>(coarse, ln_c_g, ln_c_b, w_gate, b_gate,
                                            WfragC_hi, WfragC_lo, b_qc, b_k, b_v,
                                            gate, qc, key_pk, val_b);
    k_query_fused<<<2048, 256, 0, stream>>>(fine, ln_f_g, ln_f_b, WfragQ_hi, WfragQ_lo, b_qf,
                                            gate, qc, QF);
    k_attn_mfma<<<1024, 256, 0, stream>>>(QF, key_pk, val_b, out);
}